// Round 5
// baseline (403.156 us; speedup 1.0000x reference)
//
#include <hip/hip_runtime.h>
#include <hip/hip_bf16.h>

// Problem constants
#define B_    2
#define S_    2048
#define E_    2048
#define H_    16
#define HKV_  4
#define D_    128
#define NTOK  4096      // B_*S_
#define KVDIM 512       // HKV_*D_

typedef __bf16 bf16x8 __attribute__((ext_vector_type(8)));
typedef __bf16 bf16x4 __attribute__((ext_vector_type(4)));
typedef float  f32x4  __attribute__((ext_vector_type(4)));

__device__ __forceinline__ void async_copy16(const void* g, void* l) {
  // 16B per lane; LDS dest = wave-uniform base + lane*16 (m104/m108 semantics)
  __builtin_amdgcn_global_load_lds(
      (const __attribute__((address_space(1))) unsigned int*)g,
      (__attribute__((address_space(3))) unsigned int*)l, 16, 0, 0);
}

// ---------------------------------------------------------------------------
// Fused 4-weight transpose+convert: fp32 [R][C] -> bf16 [C][R], z selects W.
// ---------------------------------------------------------------------------
__global__ __launch_bounds__(256) void transpose_all(
    const float* __restrict__ Wq, const float* __restrict__ Wk,
    const float* __restrict__ Wv, const float* __restrict__ Wo,
    __bf16* __restrict__ WTq, __bf16* __restrict__ WTk,
    __bf16* __restrict__ WTv, __bf16* __restrict__ WoT) {
  const float* in;
  __bf16* out;
  int C;
  switch (blockIdx.z) {
    case 0:  in = Wq; out = WTq; C = E_;   break;
    case 1:  in = Wk; out = WTk; C = KVDIM; break;
    case 2:  in = Wv; out = WTv; C = KVDIM; break;
    default: in = Wo; out = WoT; C = E_;   break;
  }
  const int c0 = blockIdx.x * 32;
  if (c0 >= C) return;  // uniform early-exit (idle z=1/2 blocks)
  const int r0 = blockIdx.y * 32;
  __shared__ float t[32][33];
  const int tr = threadIdx.x >> 3;        // 0..31
  const int tc = (threadIdx.x & 7) * 4;   // 0..28 step 4
  const float* ip = in + (size_t)(r0 + tr) * C + c0 + tc;
#pragma unroll
  for (int i = 0; i < 4; ++i) t[tr][tc + i] = ip[i];
  __syncthreads();
  __bf16* op = out + (size_t)(c0 + tr) * E_ + r0 + tc;  // R==E_ for all
#pragma unroll
  for (int i = 0; i < 4; ++i) op[i] = (__bf16)t[tc + i][tr];
}

// ---------------------------------------------------------------------------
// Fused QKV projection GEMM. A fp32 (converted during staging); B bf16 async.
// 1-D grid 768, XCD-aware swizzle: all 24 n-blocks of an m-tile land on the
// same XCD (XCD = g % 8 round-robin) so the A-tile is L2-resident.
//   bx 0..15  : query @ WTq -> Qp   (N=2048)
//   bx 16..19 : key   @ WTk -> Kp   (N=512)
//   bx 20..23 : value @ WTv -> Vt   (N=512, scatter [b][hkv][d][s])
// ---------------------------------------------------------------------------
__global__ __launch_bounds__(256, 2) void gemm_qkv(
    const float* __restrict__ query, const float* __restrict__ key,
    const float* __restrict__ value, const __bf16* __restrict__ WTq,
    const __bf16* __restrict__ WTk, const __bf16* __restrict__ WTv,
    __bf16* __restrict__ Qp, __bf16* __restrict__ Kp,
    __bf16* __restrict__ Vt) {
  __shared__ __align__(16) __bf16 As[128 * 32];
  __shared__ __align__(16) __bf16 Bs[128 * 32];

  // swizzle: g -> (bx, by) with by ≡ g (mod 8)  => same-m0 blocks share XCD
  const int g = blockIdx.x;
  const int bx = (g >> 3) % 24;
  const int by = (g & 7) | (((g >> 3) / 24) << 3);

  const float* A;
  const __bf16* Bt;
  int n0, N, epi;
  if (bx < 16)      { A = query; Bt = WTq; n0 = bx * 128;        N = E_;    epi = 0; }
  else if (bx < 20) { A = key;   Bt = WTk; n0 = (bx - 16) * 128; N = KVDIM; epi = 0; }
  else              { A = value; Bt = WTv; n0 = (bx - 20) * 128; N = KVDIM; epi = 1; }
  const int m0 = by * 128;
  const int K = E_;

  const int tid = threadIdx.x;
  const int w = tid >> 6;
  const int lane = tid & 63;
  const int quad = lane >> 4;
  const int l16 = lane & 15;
  const int wr = w >> 1, wc = w & 1;
  const int brow = lane >> 2;          // 0..15
  const int bcol = (lane & 3) * 8;     // 0,8,16,24
  const int arow = lane >> 2;
  const int acol = (lane & 3) * 8;

  f32x4 acc[4][4] = {};

  for (int k0 = 0; k0 < K; k0 += 32) {
    __syncthreads();
    // B: async bf16 16B/lane, 2 chunks/wave
#pragma unroll
    for (int c = 0; c < 2; ++c) {
      const int chunk = w * 2 + c;
      const int row = chunk * 16 + brow;
      async_copy16(Bt + (size_t)(n0 + row) * K + k0 + bcol, &Bs[chunk * 512]);
    }
    // A: fp32 -> bf16 convert during staging (VGPR roundtrip)
#pragma unroll
    for (int s = 0; s < 2; ++s) {
      const int row = w * 32 + s * 16 + arow;
      const float* src = A + (size_t)(m0 + row) * K + k0 + acol;
      const f32x4 a0 = *(const f32x4*)src;
      const f32x4 a1 = *(const f32x4*)(src + 4);
      bf16x8 v;
#pragma unroll
      for (int j = 0; j < 4; ++j) { v[j] = (__bf16)a0[j]; v[4 + j] = (__bf16)a1[j]; }
      *(bf16x8*)&As[row * 32 + acol] = v;
    }
    __syncthreads();
    bf16x8 af[4], bfr[4];
#pragma unroll
    for (int i = 0; i < 4; ++i)
      af[i] = *(const bf16x8*)&As[(wr * 64 + i * 16 + l16) * 32 + quad * 8];
#pragma unroll
    for (int j = 0; j < 4; ++j)
      bfr[j] = *(const bf16x8*)&Bs[(wc * 64 + j * 16 + l16) * 32 + quad * 8];
#pragma unroll
    for (int i = 0; i < 4; ++i)
#pragma unroll
      for (int j = 0; j < 4; ++j)
        acc[i][j] = __builtin_amdgcn_mfma_f32_16x16x32_bf16(af[i], bfr[j],
                                                            acc[i][j], 0, 0, 0);
  }

  // C/D layout: col = lane&15 (n), row = quad*4 + reg (m). [m89/m91]
#pragma unroll
  for (int i = 0; i < 4; ++i) {
#pragma unroll
    for (int j = 0; j < 4; ++j) {
#pragma unroll
      for (int r = 0; r < 4; ++r) {
        const int m = m0 + wr * 64 + i * 16 + quad * 4 + r;
        const int n = n0 + wc * 64 + j * 16 + l16;
        if (epi == 0) {
          __bf16* C = (bx < 16) ? Qp : Kp;
          C[(size_t)m * N + n] = (__bf16)acc[i][j][r];
        } else {
          const int b = m >> 11, s = m & (S_ - 1);
          Vt[((size_t)((b * HKV_ + (n >> 7)) * D_ + (n & (D_ - 1)))) * S_ + s] =
              (__bf16)acc[i][j][r];
        }
      }
    }
  }
}

// ---------------------------------------------------------------------------
// O-projection GEMM: C fp32 = A bf16 @ Bt bf16^T. m97 + XCD swizzle (16 bx).
// ---------------------------------------------------------------------------
__global__ __launch_bounds__(256, 2) void gemm_o(
    const __bf16* __restrict__ A, const __bf16* __restrict__ Bt,
    float* __restrict__ Cout, int M, int N, int K) {
  __shared__ __align__(16) __bf16 As[128 * 32];
  __shared__ __align__(16) __bf16 Bs[128 * 32];
  const int g = blockIdx.x;
  const int bx = (g >> 3) % 16;
  const int by = (g & 7) | (((g >> 3) / 16) << 3);
  const int m0 = by * 128;
  const int n0 = bx * 128;
  const int tid = threadIdx.x;
  const int w = tid >> 6;
  const int lane = tid & 63;
  const int quad = lane >> 4;
  const int l16 = lane & 15;
  const int wr = w >> 1, wc = w & 1;
  const int arow = lane >> 2;
  const int acol = (lane & 3) * 8;

  f32x4 acc[4][4] = {};

  for (int k0 = 0; k0 < K; k0 += 32) {
    __syncthreads();
#pragma unroll
    for (int c = 0; c < 2; ++c) {
      const int chunk = w * 2 + c;
      const int row = chunk * 16 + arow;
      async_copy16(A + (size_t)(m0 + row) * K + k0 + acol, &As[chunk * 512]);
      async_copy16(Bt + (size_t)(n0 + row) * K + k0 + acol, &Bs[chunk * 512]);
    }
    __syncthreads();
    bf16x8 af[4], bfr[4];
#pragma unroll
    for (int i = 0; i < 4; ++i)
      af[i] = *(const bf16x8*)&As[(wr * 64 + i * 16 + l16) * 32 + quad * 8];
#pragma unroll
    for (int j = 0; j < 4; ++j)
      bfr[j] = *(const bf16x8*)&Bs[(wc * 64 + j * 16 + l16) * 32 + quad * 8];
#pragma unroll
    for (int i = 0; i < 4; ++i)
#pragma unroll
      for (int j = 0; j < 4; ++j)
        acc[i][j] = __builtin_amdgcn_mfma_f32_16x16x32_bf16(af[i], bfr[j],
                                                            acc[i][j], 0, 0, 0);
  }

#pragma unroll
  for (int i = 0; i < 4; ++i)
#pragma unroll
    for (int j = 0; j < 4; ++j)
#pragma unroll
      for (int r = 0; r < 4; ++r) {
        const int m = m0 + wr * 64 + i * 16 + quad * 4 + r;
        const int n = n0 + wc * 64 + j * 16 + l16;
        Cout[(size_t)m * N + n] = acc[i][j][r];
      }
}

// ---------------------------------------------------------------------------
// Flash attention (unchanged): block = 128 q-rows of one (b,h).
// ---------------------------------------------------------------------------
__global__ __launch_bounds__(256, 2) void attn_kernel(
    const __bf16* __restrict__ Q, const __bf16* __restrict__ Kp,
    const __bf16* __restrict__ Vt, const float* __restrict__ mask,
    __bf16* __restrict__ Oa) {
  __shared__ __align__(16) __bf16 K_lds[64][136];
  __shared__ __align__(16) __bf16 V_lds[128][72];
  __shared__ __align__(16) __bf16 P_lds[4][32][72];

  const int tid = threadIdx.x;
  const int w = tid >> 6, lane = tid & 63, quad = lane >> 4, l16 = lane & 15;
  const int bh = blockIdx.y;
  const int b = bh >> 4, h = bh & 15, hkv = h >> 2;
  const int q0 = blockIdx.x * 128 + w * 32;

  const __bf16* qbase = Q + (size_t)(b * S_ + q0) * E_ + h * D_;
  bf16x8 qf[2][4];
#pragma unroll
  for (int m = 0; m < 2; ++m)
#pragma unroll
    for (int ks = 0; ks < 4; ++ks)
      qf[m][ks] = *(const bf16x8*)(qbase + (size_t)(m * 16 + l16) * E_ +
                                   ks * 32 + quad * 8);

  const __bf16* kbase = Kp + (size_t)(b * S_) * KVDIM + hkv * D_;
  const __bf16* vbase = Vt + (size_t)((b * HKV_ + hkv) * D_) * S_;
  const float* mbase = mask + b * S_;

  f32x4 o[2][8] = {};
  f32x4 lsum[2] = {};
  const float scale = 0.08838834764831845f;  // 1/sqrt(128)

  for (int kt = 0; kt < S_; kt += 64) {
    __syncthreads();
#pragma unroll
    for (int i = 0; i < 4; ++i) {
      const int r = w * 16 + i * 4 + (lane >> 4);
      bf16x8 kv = *(const bf16x8*)(kbase + (size_t)(kt + r) * KVDIM +
                                   (lane & 15) * 8);
      *(bf16x8*)&K_lds[r][(lane & 15) * 8] = kv;
    }
#pragma unroll
    for (int i = 0; i < 4; ++i) {
      const int r = w * 32 + i * 8 + (lane >> 3);
      bf16x8 vv = *(const bf16x8*)(vbase + (size_t)r * S_ + kt +
                                   (lane & 7) * 8);
      *(bf16x8*)&V_lds[r][(lane & 7) * 8] = vv;
    }
    __syncthreads();

    f32x4 s[2][4] = {};
#pragma unroll
    for (int ks = 0; ks < 4; ++ks) {
#pragma unroll
      for (int n = 0; n < 4; ++n) {
        bf16x8 kf = *(const bf16x8*)&K_lds[n * 16 + l16][ks * 32 + quad * 8];
        s[0][n] = __builtin_amdgcn_mfma_f32_16x16x32_bf16(qf[0][ks], kf,
                                                          s[0][n], 0, 0, 0);
        s[1][n] = __builtin_amdgcn_mfma_f32_16x16x32_bf16(qf[1][ks], kf,
                                                          s[1][n], 0, 0, 0);
      }
    }

    float bias[4];
#pragma unroll
    for (int n = 0; n < 4; ++n)
      bias[n] = (1.0f - mbase[kt + n * 16 + l16]) * -1e9f;
#pragma unroll
    for (int m = 0; m < 2; ++m) {
#pragma unroll
      for (int n = 0; n < 4; ++n) {
#pragma unroll
        for (int r = 0; r < 4; ++r) {
          const float p = __expf(s[m][n][r] * scale + bias[n]);
          lsum[m][r] += p;
          P_lds[w][m * 16 + quad * 4 + r][n * 16 + l16] = (__bf16)p;
        }
      }
    }

#pragma unroll
    for (int ks2 = 0; ks2 < 2; ++ks2) {
      bf16x8 pa[2];
#pragma unroll
      for (int m = 0; m < 2; ++m)
        pa[m] = *(const bf16x8*)&P_lds[w][m * 16 + l16][ks2 * 32 + quad * 8];
#pragma unroll
      for (int dt = 0; dt < 8; ++dt) {
        bf16x8 vf = *(const bf16x8*)&V_lds[dt * 16 + l16][ks2 * 32 + quad * 8];
        o[0][dt] = __builtin_amdgcn_mfma_f32_16x16x32_bf16(pa[0], vf,
                                                           o[0][dt], 0, 0, 0);
        o[1][dt] = __builtin_amdgcn_mfma_f32_16x16x32_bf16(pa[1], vf,
                                                           o[1][dt], 0, 0, 0);
      }
    }
  }

  __bf16* obase = Oa + (size_t)(b * S_ + q0) * E_ + h * D_;
#pragma unroll
  for (int m = 0; m < 2; ++m) {
#pragma unroll
    for (int r = 0; r < 4; ++r) {
      float v = lsum[m][r];
#pragma unroll
      for (int off = 1; off < 16; off <<= 1) v += __shfl_xor(v, off);
      const float inv = 1.0f / v;
#pragma unroll
      for (int dt = 0; dt < 8; ++dt)
        obase[(size_t)(m * 16 + quad * 4 + r) * E_ + dt * 16 + l16] =
            (__bf16)(o[m][dt][r] * inv);
    }
  }
}

// ---------------------------------------------------------------------------
extern "C" void kernel_launch(void* const* d_in, const int* in_sizes, int n_in,
                              void* d_out, int out_size, void* d_ws,
                              size_t ws_size, hipStream_t stream) {
  const float* query = (const float*)d_in[0];
  const float* key   = (const float*)d_in[1];
  const float* value = (const float*)d_in[2];
  const float* mask  = (const float*)d_in[3];
  const float* Wq    = (const float*)d_in[4];
  const float* Wk    = (const float*)d_in[5];
  const float* Wv    = (const float*)d_in[6];
  const float* Wo    = (const float*)d_in[7];
  float* out = (float*)d_out;

  // Workspace 48 MB (known-safe), bf16 elements:
  //   Qp 16MB | Kp 4MB | Vt 4MB | WoT 8MB | WTq 8MB | WTk 2MB | WTv 2MB
  // Attn (16MB) overlaps [WTq|WTk|WTv|spare] — consumed before attention runs.
  __bf16* ws   = (__bf16*)d_ws;
  __bf16* Qp   = ws;                           // @ 0
  __bf16* Kp   = Qp + (size_t)NTOK * E_;       // @ 16MB
  __bf16* Vt   = Kp + (size_t)NTOK * KVDIM;    // @ 20MB
  __bf16* WoT  = Vt + (size_t)NTOK * KVDIM;    // @ 24MB
  __bf16* WTq  = WoT + (size_t)E_ * E_;        // @ 32MB
  __bf16* WTk  = WTq + (size_t)E_ * E_;        // @ 40MB
  __bf16* WTv  = WTk + (size_t)KVDIM * E_;     // @ 42MB
  __bf16* Attn = WTq;                          // @ 32MB (16MB, reuse)

  // 1) all weight transposes in one launch
  transpose_all<<<dim3(64, 64, 4), 256, 0, stream>>>(Wq, Wk, Wv, Wo,
                                                     WTq, WTk, WTv, WoT);
  // 2) fused QKV projection (XCD-swizzled 1-D grid)
  gemm_qkv<<<768, 256, 0, stream>>>(query, key, value,
                                    WTq, WTk, WTv, Qp, Kp, Vt);
  // 3) attention -> Attn (clobbers WTq/k/v, already consumed)
  attn_kernel<<<dim3(S_ / 128, B_ * H_), 256, 0, stream>>>(Qp, Kp, Vt, mask,
                                                           Attn);
  // 4) output projection (XCD-swizzled 1-D grid, fp32 epilogue to d_out)
  gemm_o<<<512, 256, 0, stream>>>(Attn, WoT, out, NTOK, E_, E_);
}